// Round 6
// baseline (218.943 us; speedup 1.0000x reference)
//
#include <hip/hip_runtime.h>
#include <math.h>

// Problem constants: B=128, N=512, PD=512, E=64, gamma=1
#define Bb   128
#define Nn   512
#define Ee   64
#define NCr  192
#define CGIT 28

typedef float vf4 __attribute__((ext_vector_type(4)));

struct CCoef { float cq[5], cr[5], f4, f2; };

__device__ __forceinline__ float wred(float v)
{
    #pragma unroll
    for (int s = 32; s > 0; s >>= 1) v += __shfl_xor(v, s, 64);
    return v;
}

// ---------------------------------------------------------------------------
// k_prep: Y = M @ M (512^3 fp32). 64 WGs x 256 thr, 64x64 tile, 4x4 micro.
// A-tile stored k-major (transposed) so both fragment reads are float4.
// ---------------------------------------------------------------------------
__global__ __launch_bounds__(256) void k_prep(const float* __restrict__ Mm,
                                              float* __restrict__ Y)
{
    __shared__ float As[16][68];   // [k][row]
    __shared__ float Bs[16][68];   // [k][col]
    const int t  = threadIdx.x;
    const int tx = t & 15, ty = t >> 4;
    const int r0 = (int)(blockIdx.x >> 3) * 64;
    const int c0 = (int)(blockIdx.x & 7) * 64;
    const int lrow = t & 63, lc4 = t >> 6;

    vf4 acc0 = {0,0,0,0}, acc1 = {0,0,0,0}, acc2 = {0,0,0,0}, acc3 = {0,0,0,0};

    for (int k0 = 0; k0 < Nn; k0 += 16) {
        vf4 a = *(const vf4*)(Mm + (r0 + lrow) * Nn + k0 + 4 * lc4);
        vf4 b = *(const vf4*)(Mm + (k0 + ty) * Nn + c0 + 4 * tx);
        __syncthreads();
        As[4*lc4+0][lrow] = a.x; As[4*lc4+1][lrow] = a.y;
        As[4*lc4+2][lrow] = a.z; As[4*lc4+3][lrow] = a.w;
        *(vf4*)&Bs[ty][4*tx] = b;
        __syncthreads();
        #pragma unroll
        for (int kk = 0; kk < 16; ++kk) {
            vf4 av = *(const vf4*)&As[kk][4*ty];
            vf4 bv = *(const vf4*)&Bs[kk][4*tx];
            acc0 += bv * av.x; acc1 += bv * av.y;
            acc2 += bv * av.z; acc3 += bv * av.w;
        }
    }
    float* yp = Y + (r0 + 4*ty) * Nn + c0 + 4*tx;
    *(vf4*)(yp)          = acc0;
    *(vf4*)(yp + Nn)     = acc1;
    *(vf4*)(yp + 2*Nn)   = acc2;
    *(vf4*)(yp + 3*Nn)   = acc3;
}

// ---------------------------------------------------------------------------
// k_solve: 96 WGs x 512 thr. WG owns rows {2wg, 2wg+1} of [X-P | A0^T].
// p(M)v = q(Y)v + M r(Y)v via Clenshaw: 4 Y-passes + 1 M-pass, zero grid
// syncs. Inner loops software-pipelined (depth-1 register prefetch).
// ---------------------------------------------------------------------------
__global__ __launch_bounds__(512, 2) void k_solve(
    const float* __restrict__ x, const float* __restrict__ p,
    const float* __restrict__ Mm, const float* __restrict__ Y,
    const float* __restrict__ A0, const float* __restrict__ cvec,
    float* __restrict__ u_g, float* __restrict__ su, CCoef cf)
{
    __shared__ float L[9216];        // 36 KB
    float* v0  = L;                  // [2][512] input rows, later uS
    float* qb1 = L + 1024;
    float* qb2 = L + 2048;
    float* rb1 = L + 3072;
    float* rb2 = L + 4096;
    float* yqA = L + 5120;
    float* yrA = L + 6144;
    float* yqB = L + 7168;
    float* yrB = L + 8192;

    const int t    = threadIdx.x;
    const int wg   = blockIdx.x;
    const int row0 = wg * 2;
    const int j    = t & 127;        // cols 4j..4j+3
    const int kq   = t >> 7;         // K-quarter 0..3
    const int kb0  = kq * 128;

    // build rows + Clenshaw init: b4 = c4*v0, b5 = 0
    for (int i = t; i < 1024; i += 512) {
        int m = i >> 9, n = i & 511, gr = row0 + m;
        float v = (gr < Bb) ? (x[gr * Nn + n] - p[gr * Nn + n])
                            : A0[(gr - Bb) * Nn + n];
        v0[i] = v;
        qb1[i] = cf.cq[4] * v; qb2[i] = 0.f;
        rb1[i] = cf.cr[4] * v; rb2[i] = 0.f;
    }
    __syncthreads();

    // 4 Y-passes (Clenshaw steps + final combine)
    for (int step = 0; step < 4; ++step) {
        vf4 aq0 = {0,0,0,0}, aq1 = {0,0,0,0}, ar0 = {0,0,0,0}, ar1 = {0,0,0,0};
        const float* Yp = Y + kb0 * Nn + 4 * j;
        vf4 y0 = *(const vf4*)(Yp);
        vf4 y1 = *(const vf4*)(Yp + Nn);
        vf4 y2 = *(const vf4*)(Yp + 2*Nn);
        vf4 y3 = *(const vf4*)(Yp + 3*Nn);
        vf4 q0 = *(const vf4*)&qb1[kb0],       q1 = *(const vf4*)&qb1[512 + kb0];
        vf4 r0 = *(const vf4*)&rb1[kb0],       r1 = *(const vf4*)&rb1[512 + kb0];
        #pragma unroll 4
        for (int k4 = 0; k4 < 32; ++k4) {
            const int adv = (k4 < 31) ? 4 : 0;
            const float* Yn = Yp + adv * Nn;
            const int kn = kb0 + 4 * k4 + adv;
            vf4 p0 = *(const vf4*)(Yn);
            vf4 p1 = *(const vf4*)(Yn + Nn);
            vf4 p2 = *(const vf4*)(Yn + 2*Nn);
            vf4 p3 = *(const vf4*)(Yn + 3*Nn);
            vf4 nq0 = *(const vf4*)&qb1[kn], nq1 = *(const vf4*)&qb1[512 + kn];
            vf4 nr0 = *(const vf4*)&rb1[kn], nr1 = *(const vf4*)&rb1[512 + kn];
            aq0 += y0*q0.x; aq0 += y1*q0.y; aq0 += y2*q0.z; aq0 += y3*q0.w;
            aq1 += y0*q1.x; aq1 += y1*q1.y; aq1 += y2*q1.z; aq1 += y3*q1.w;
            ar0 += y0*r0.x; ar0 += y1*r0.y; ar0 += y2*r0.z; ar0 += y3*r0.w;
            ar1 += y0*r1.x; ar1 += y1*r1.y; ar1 += y2*r1.z; ar1 += y3*r1.w;
            y0 = p0; y1 = p1; y2 = p2; y3 = p3;
            q0 = nq0; q1 = nq1; r0 = nr0; r1 = nr1;
            Yp = Yn;
        }
        // 2-buffer split-K reduce: kq0/kq1 write A/B, kq2/kq3 add A/B
        float* tq = (kq & 1) ? yqB : yqA;
        float* tr = (kq & 1) ? yrB : yrA;
        if (kq < 2) {
            *(vf4*)&tq[4*j] = aq0; *(vf4*)&tq[512 + 4*j] = aq1;
            *(vf4*)&tr[4*j] = ar0; *(vf4*)&tr[512 + 4*j] = ar1;
        }
        __syncthreads();
        if (kq >= 2) {
            vf4 v;
            v = *(vf4*)&tq[4*j];       v += aq0; *(vf4*)&tq[4*j] = v;
            v = *(vf4*)&tq[512+4*j];   v += aq1; *(vf4*)&tq[512+4*j] = v;
            v = *(vf4*)&tr[4*j];       v += ar0; *(vf4*)&tr[4*j] = v;
            v = *(vf4*)&tr[512+4*j];   v += ar1; *(vf4*)&tr[512+4*j] = v;
        }
        __syncthreads();

        if (step < 3) {
            float cqj = cf.cq[3 - step], crj = cf.cr[3 - step];
            for (int i = t; i < 1024; i += 512) {
                float yvq = yqA[i] + yqB[i];
                float yvr = yrA[i] + yrB[i];
                float bnq = cqj * v0[i] + cf.f4 * yvq - 2.f * qb1[i] - qb2[i];
                float bnr = crj * v0[i] + cf.f4 * yvr - 2.f * rb1[i] - rb2[i];
                qb2[i] = qb1[i]; qb1[i] = bnq;
                rb2[i] = rb1[i]; rb1[i] = bnr;
            }
        } else {   // final: F = c0 v0 + s b1 - b2,  s b1 = f2*Yb1 - b1
            for (int i = t; i < 1024; i += 512) {
                float yvq = yqA[i] + yqB[i];
                float yvr = yrA[i] + yrB[i];
                float Fq = cf.cq[0] * v0[i] + cf.f2 * yvq - qb1[i] - qb2[i];
                float Fr = cf.cr[0] * v0[i] + cf.f2 * yvr - rb1[i] - rb2[i];
                qb1[i] = Fq; rb1[i] = Fr;
            }
        }
        __syncthreads();
    }

    // final M-pass: u = Fq + M*Fr (software-pipelined)
    {
        vf4 am0 = {0,0,0,0}, am1 = {0,0,0,0};
        const float* Mp = Mm + kb0 * Nn + 4 * j;
        vf4 y0 = *(const vf4*)(Mp);
        vf4 y1 = *(const vf4*)(Mp + Nn);
        vf4 y2 = *(const vf4*)(Mp + 2*Nn);
        vf4 y3 = *(const vf4*)(Mp + 3*Nn);
        vf4 r0 = *(const vf4*)&rb1[kb0], r1 = *(const vf4*)&rb1[512 + kb0];
        #pragma unroll 4
        for (int k4 = 0; k4 < 32; ++k4) {
            const int adv = (k4 < 31) ? 4 : 0;
            const float* Mn = Mp + adv * Nn;
            const int kn = kb0 + 4 * k4 + adv;
            vf4 p0 = *(const vf4*)(Mn);
            vf4 p1 = *(const vf4*)(Mn + Nn);
            vf4 p2 = *(const vf4*)(Mn + 2*Nn);
            vf4 p3 = *(const vf4*)(Mn + 3*Nn);
            vf4 nr0 = *(const vf4*)&rb1[kn], nr1 = *(const vf4*)&rb1[512 + kn];
            am0 += y0*r0.x; am0 += y1*r0.y; am0 += y2*r0.z; am0 += y3*r0.w;
            am1 += y0*r1.x; am1 += y1*r1.y; am1 += y2*r1.z; am1 += y3*r1.w;
            y0 = p0; y1 = p1; y2 = p2; y3 = p3;
            r0 = nr0; r1 = nr1;
            Mp = Mn;
        }
        float* tq = (kq & 1) ? yqB : yqA;
        if (kq < 2) { *(vf4*)&tq[4*j] = am0; *(vf4*)&tq[512+4*j] = am1; }
        __syncthreads();
        if (kq >= 2) {
            vf4 v;
            v = *(vf4*)&tq[4*j];     v += am0; *(vf4*)&tq[4*j] = v;
            v = *(vf4*)&tq[512+4*j]; v += am1; *(vf4*)&tq[512+4*j] = v;
        }
        __syncthreads();
        for (int i = t; i < 1024; i += 512) {
            float uv = qb1[i] + yqA[i] + yqB[i];
            v0[i] = uv;                                       // uS
            u_g[(row0 + (i >> 9)) * Nn + (i & 511)] = uv;
        }
        __syncthreads();
    }

    // fused Schur assembly: this WG's two su columns
    {
        float* As = L + 1024;       // [64][33] (qb region dead)
        float* Ps = L + 3200;       // [8][64]  (rb region dead)
        float accS = 0.f;
        const int e = t & 63;
        const int sub = t >> 6;                 // 0..7
        const int m_ = sub & 1, ch = sub >> 1;  // row, k-chunk 0..3
        for (int k0 = 0; k0 < Nn; k0 += 32) {
            __syncthreads();
            for (int i = t; i < 2048; i += 512) {
                int ee = i >> 5, cc = i & 31;
                As[ee * 33 + cc] = A0[ee * Nn + k0 + cc];
            }
            __syncthreads();
            #pragma unroll
            for (int cc = 0; cc < 8; ++cc)
                accS += As[e * 33 + ch * 8 + cc] * v0[m_ * 512 + k0 + ch * 8 + cc];
        }
        Ps[sub * 64 + e] = accS;
        __syncthreads();
        if (t < 128) {
            int mm = t >> 6, ee = t & 63;
            float val = Ps[mm * 64 + ee] + Ps[(mm + 2) * 64 + ee]
                      + Ps[(mm + 4) * 64 + ee] + Ps[(mm + 6) * 64 + ee];
            int gr = row0 + mm;
            int jj = (gr < Bb) ? (64 + gr) : (gr - Bb);
            su[ee * NCr + jj] = val + ((jj >= 64) ? cvec[ee] : 0.f);
        }
    }
}

// ---------------------------------------------------------------------------
// k_lam_final: CG on S (64x64 SPD) for 128 columns, 1 wave/column, then
// out[b] = T_b - V * Lambda_b.  16 WGs x 512 thr.
// ---------------------------------------------------------------------------
__global__ __launch_bounds__(512) void k_lam_final(
    const float* __restrict__ u_g, const float* __restrict__ su,
    float* __restrict__ out)
{
    __shared__ float Sm[64][65];
    __shared__ float pb[8][64];
    const int t = threadIdx.x, w = t >> 6, lane = t & 63;

    for (int i = t; i < 64 * 64; i += 512)
        Sm[i >> 6][i & 63] = su[(i >> 6) * NCr + (i & 63)];
    __syncthreads();

    const int b = blockIdx.x * 8 + w;
    float srow[64];
    #pragma unroll
    for (int k = 0; k < 64; ++k) srow[k] = Sm[lane][k];

    float rhs = su[lane * NCr + 64 + b];
    float xv = 0.f, rv = rhs, pv = rv;
    float rr = wred(rv * rv);
    for (int itc = 0; itc < CGIT; ++itc) {
        pb[w][lane] = pv;
        float q = 0.f;
        #pragma unroll
        for (int k = 0; k < 64; ++k) q += srow[k] * pb[w][k];
        float pq = wred(pv * q);
        float alpha = rr / fmaxf(pq, 1e-30f);
        xv += alpha * pv;
        rv -= alpha * q;
        float rr2 = wred(rv * rv);
        float beta = rr2 / fmaxf(rr, 1e-30f);
        rr = rr2;
        pv = rv + beta * pv;
    }
    pb[w][lane] = xv;

    #pragma unroll
    for (int i = 0; i < 8; ++i) {
        int n = lane + 64 * i;
        float acc = u_g[b * Nn + n];
        #pragma unroll 4
        for (int e = 0; e < Ee; ++e)
            acc -= pb[w][e] * u_g[(Bb + e) * Nn + n];
        out[b * Nn + n] = acc;
    }
}

// ---------------------------------------------------------------------------
extern "C" void kernel_launch(void* const* d_in, const int* in_sizes, int n_in,
                              void* d_out, int out_size, void* d_ws, size_t ws_size,
                              hipStream_t stream)
{
    const float* x     = (const float*)d_in[0];
    const float* parms = (const float*)d_in[1];
    const float* Mm    = (const float*)d_in[2];
    const float* A0    = (const float*)d_in[3];
    // d_in[4] = B0 unused (F at zeros -> only c survives)
    const float* c     = (const float*)d_in[5];
    float* out = (float*)d_out;

    float* ws  = (float*)d_ws;
    float* Y   = ws;                         // 512*512
    float* u_g = ws + Nn * Nn;               // 192*512
    float* su  = ws + Nn * Nn + NCr * Nn;    // 64*192

    // ---- host: degree-9 Chebyshev poly for 1/h on [1, 3.12], even/odd split,
    // converted to Chebyshev basis on y = m^2 in [0, ymax] (all double).
    const double aa = 1.0, bbound = 3.12;
    const double th = 0.5 * (bbound + aa), de = 0.5 * (bbound - aa), sg = th / de;
    double rp[16] = {0}, dp[16] = {0}, xp[16] = {0}, hd[16];
    rp[0] = 1.0; dp[0] = 1.0 / th; xp[0] = 1.0 / th;
    double rho_prev = 1.0 / sg;
    for (int k = 1; k <= 9; ++k) {
        double rho = 1.0 / (2.0 * sg - rho_prev);
        double C1 = rho * rho_prev, C2 = 2.0 * rho / de;
        for (int i = 15; i >= 1; --i) hd[i] = dp[i - 1];
        hd[0] = 0.0;
        for (int i = 0; i < 16; ++i) {
            rp[i] -= hd[i];
            dp[i] = C1 * dp[i] + C2 * rp[i];
            xp[i] += dp[i];
        }
        rho_prev = rho;
    }
    // substitute h = 1 + m/2
    double pm[16] = {0};
    for (int k = 0; k <= 9; ++k) {
        double term[16] = {0}; term[0] = 1.0;
        for (int e = 0; e < k; ++e) {
            double nt[16] = {0};
            for (int i = 0; i <= e; ++i) { nt[i] += term[i]; nt[i + 1] += 0.5 * term[i]; }
            for (int i = 0; i <= e + 1; ++i) term[i] = nt[i];
        }
        for (int i = 0; i <= k; ++i) pm[i] += xp[k] * term[i];
    }
    double qm[8] = {0}, rm[8] = {0};
    for (int jj = 0; jj < 5; ++jj) { qm[jj] = pm[2 * jj]; rm[jj] = pm[2 * jj + 1]; }
    const double mmax = 2.0 * (bbound - 1.0);
    const double ymax = mmax * mmax;
    double cq[5] = {0}, cr[5] = {0};
    const int NP = 64;
    for (int i = 0; i < NP; ++i) {
        double thn = M_PI * (i + 0.5) / NP;
        double s = cos(thn);
        double y = 0.5 * ymax * (s + 1.0);
        double vq = 0, vr = 0;
        for (int d2 = 4; d2 >= 0; --d2) { vq = vq * y + qm[d2]; vr = vr * y + rm[d2]; }
        for (int jj = 0; jj < 5; ++jj) {
            cq[jj] += (2.0 / NP) * vq * cos(jj * thn);
            cr[jj] += (2.0 / NP) * vr * cos(jj * thn);
        }
    }
    cq[0] *= 0.5; cr[0] *= 0.5;
    CCoef cf;
    for (int jj = 0; jj < 5; ++jj) { cf.cq[jj] = (float)cq[jj]; cf.cr[jj] = (float)cr[jj]; }
    cf.f4 = (float)(4.0 / ymax);
    cf.f2 = (float)(2.0 / ymax);

    hipLaunchKernelGGL(k_prep,      dim3(64),  dim3(256), 0, stream, Mm, Y);
    hipLaunchKernelGGL(k_solve,     dim3(96),  dim3(512), 0, stream,
                       x, parms, Mm, Y, A0, c, u_g, su, cf);
    hipLaunchKernelGGL(k_lam_final, dim3(16),  dim3(512), 0, stream, u_g, su, out);
}

// Round 7
// 208.564 us; speedup vs baseline: 1.0498x; 1.0498x over previous
//
#include <hip/hip_runtime.h>
#include <math.h>

// Problem constants: B=128, N=512, PD=512, E=64, gamma=1
#define Bb   128
#define Nn   512
#define Ee   64
#define NCr  192
#define CGIT 22

typedef float vf4 __attribute__((ext_vector_type(4)));

struct CCoef { float cq[5], cr[5], f4, f2; };

__device__ __forceinline__ float wred(float v)
{
    #pragma unroll
    for (int s = 32; s > 0; s >>= 1) v += __shfl_xor(v, s, 64);
    return v;
}

// ---------------------------------------------------------------------------
// k_prep: Y = M @ M (512^3 fp32). 64 WGs x 256 thr, 64x64 tile, 4x4 micro.
// ---------------------------------------------------------------------------
__global__ __launch_bounds__(256) void k_prep(const float* __restrict__ Mm,
                                              float* __restrict__ Y)
{
    __shared__ float As[16][68];   // [k][row]
    __shared__ float Bs[16][68];   // [k][col]
    const int t  = threadIdx.x;
    const int tx = t & 15, ty = t >> 4;
    const int r0 = (int)(blockIdx.x >> 3) * 64;
    const int c0 = (int)(blockIdx.x & 7) * 64;
    const int lrow = t & 63, lc4 = t >> 6;

    vf4 acc0 = {0,0,0,0}, acc1 = {0,0,0,0}, acc2 = {0,0,0,0}, acc3 = {0,0,0,0};

    for (int k0 = 0; k0 < Nn; k0 += 16) {
        vf4 a = *(const vf4*)(Mm + (r0 + lrow) * Nn + k0 + 4 * lc4);
        vf4 b = *(const vf4*)(Mm + (k0 + ty) * Nn + c0 + 4 * tx);
        __syncthreads();
        As[4*lc4+0][lrow] = a.x; As[4*lc4+1][lrow] = a.y;
        As[4*lc4+2][lrow] = a.z; As[4*lc4+3][lrow] = a.w;
        *(vf4*)&Bs[ty][4*tx] = b;
        __syncthreads();
        #pragma unroll
        for (int kk = 0; kk < 16; ++kk) {
            vf4 av = *(const vf4*)&As[kk][4*ty];
            vf4 bv = *(const vf4*)&Bs[kk][4*tx];
            acc0 += bv * av.x; acc1 += bv * av.y;
            acc2 += bv * av.z; acc3 += bv * av.w;
        }
    }
    float* yp = Y + (r0 + 4*ty) * Nn + c0 + 4*tx;
    *(vf4*)(yp)          = acc0;
    *(vf4*)(yp + Nn)     = acc1;
    *(vf4*)(yp + 2*Nn)   = acc2;
    *(vf4*)(yp + 3*Nn)   = acc3;
}

// ---------------------------------------------------------------------------
// k_solve: 96 WGs x 1024 thr (16 waves/CU). WG owns rows {2wg,2wg+1} of
// [X-P | A0^T]. p(M)v = q(Y)v + M r(Y)v via Clenshaw: 4 Y-passes + 1 M-pass,
// zero grid syncs. Split-K=8: 64 KB of loads in flight per CU (Little's law
// target ~57 KB to saturate per-CU L2 BW). Fused Schur assembly tail.
// ---------------------------------------------------------------------------
__global__ __launch_bounds__(1024) void k_solve(
    const float* __restrict__ x, const float* __restrict__ p,
    const float* __restrict__ Mm, const float* __restrict__ Y,
    const float* __restrict__ A0, const float* __restrict__ cvec,
    float* __restrict__ u_g, float* __restrict__ su, CCoef cf)
{
    __shared__ float L[21504];       // 84 KB
    float* v0  = L;                  // [2][512] input rows, later uS
    float* qb1 = L + 1024;
    float* qb2 = L + 2048;
    float* rb1 = L + 3072;
    float* rb2 = L + 4096;
    float* PQ  = L + 5120;           // [8][1024] split-K partials, q chain
    float* PR  = L + 13312;          // [8][1024] split-K partials, r chain

    const int t    = threadIdx.x;
    const int wg   = blockIdx.x;
    const int row0 = wg * 2;
    const int j    = t & 127;        // cols 4j..4j+3
    const int kq   = t >> 7;         // K-eighth 0..7
    const int kb0  = kq * 64;

    // build rows + Clenshaw init: b4 = c4*v0, b5 = 0 (one element per thread)
    {
        int m = t >> 9, n = t & 511, gr = row0 + m;
        float v = (gr < Bb) ? (x[gr * Nn + n] - p[gr * Nn + n])
                            : A0[(gr - Bb) * Nn + n];
        v0[t] = v;
        qb1[t] = cf.cq[4] * v; qb2[t] = 0.f;
        rb1[t] = cf.cr[4] * v; rb2[t] = 0.f;
    }
    __syncthreads();

    // 4 Y-passes (Clenshaw steps + final combine)
    for (int step = 0; step < 4; ++step) {
        vf4 aq0 = {0,0,0,0}, aq1 = {0,0,0,0}, ar0 = {0,0,0,0}, ar1 = {0,0,0,0};
        const float* Yp = Y + kb0 * Nn + 4 * j;
        vf4 y0 = *(const vf4*)(Yp);
        vf4 y1 = *(const vf4*)(Yp + Nn);
        vf4 y2 = *(const vf4*)(Yp + 2*Nn);
        vf4 y3 = *(const vf4*)(Yp + 3*Nn);
        vf4 q0 = *(const vf4*)&qb1[kb0],  q1 = *(const vf4*)&qb1[512 + kb0];
        vf4 r0 = *(const vf4*)&rb1[kb0],  r1 = *(const vf4*)&rb1[512 + kb0];
        #pragma unroll 4
        for (int k4 = 0; k4 < 16; ++k4) {
            const int adv = (k4 < 15) ? 4 : 0;
            const float* Yn = Yp + adv * Nn;
            const int kn = kb0 + 4 * k4 + adv;
            vf4 p0 = *(const vf4*)(Yn);
            vf4 p1 = *(const vf4*)(Yn + Nn);
            vf4 p2 = *(const vf4*)(Yn + 2*Nn);
            vf4 p3 = *(const vf4*)(Yn + 3*Nn);
            vf4 nq0 = *(const vf4*)&qb1[kn], nq1 = *(const vf4*)&qb1[512 + kn];
            vf4 nr0 = *(const vf4*)&rb1[kn], nr1 = *(const vf4*)&rb1[512 + kn];
            aq0 += y0*q0.x; aq0 += y1*q0.y; aq0 += y2*q0.z; aq0 += y3*q0.w;
            aq1 += y0*q1.x; aq1 += y1*q1.y; aq1 += y2*q1.z; aq1 += y3*q1.w;
            ar0 += y0*r0.x; ar0 += y1*r0.y; ar0 += y2*r0.z; ar0 += y3*r0.w;
            ar1 += y0*r1.x; ar1 += y1*r1.y; ar1 += y2*r1.z; ar1 += y3*r1.w;
            y0 = p0; y1 = p1; y2 = p2; y3 = p3;
            q0 = nq0; q1 = nq1; r0 = nr0; r1 = nr1;
            Yp = Yn;
        }
        *(vf4*)&PQ[kq * 1024 + 4*j]       = aq0;
        *(vf4*)&PQ[kq * 1024 + 512 + 4*j] = aq1;
        *(vf4*)&PR[kq * 1024 + 4*j]       = ar0;
        *(vf4*)&PR[kq * 1024 + 512 + 4*j] = ar1;
        __syncthreads();

        // combine 8 partials + Clenshaw update (one element per thread)
        {
            float yvq = 0.f, yvr = 0.f;
            #pragma unroll
            for (int pp = 0; pp < 8; ++pp) {
                yvq += PQ[pp * 1024 + t];
                yvr += PR[pp * 1024 + t];
            }
            if (step < 3) {
                float cqj = cf.cq[3 - step], crj = cf.cr[3 - step];
                float bnq = cqj * v0[t] + cf.f4 * yvq - 2.f * qb1[t] - qb2[t];
                float bnr = crj * v0[t] + cf.f4 * yvr - 2.f * rb1[t] - rb2[t];
                qb2[t] = qb1[t]; qb1[t] = bnq;
                rb2[t] = rb1[t]; rb1[t] = bnr;
            } else {   // final: F = c0 v0 + s b1 - b2,  s b1 = f2*Yb1 - b1
                float Fq = cf.cq[0] * v0[t] + cf.f2 * yvq - qb1[t] - qb2[t];
                float Fr = cf.cr[0] * v0[t] + cf.f2 * yvr - rb1[t] - rb2[t];
                qb1[t] = Fq; rb1[t] = Fr;
            }
        }
        __syncthreads();
    }

    // final M-pass: u = Fq + M*Fr
    {
        vf4 am0 = {0,0,0,0}, am1 = {0,0,0,0};
        const float* Mp = Mm + kb0 * Nn + 4 * j;
        vf4 y0 = *(const vf4*)(Mp);
        vf4 y1 = *(const vf4*)(Mp + Nn);
        vf4 y2 = *(const vf4*)(Mp + 2*Nn);
        vf4 y3 = *(const vf4*)(Mp + 3*Nn);
        vf4 r0 = *(const vf4*)&rb1[kb0], r1 = *(const vf4*)&rb1[512 + kb0];
        #pragma unroll 4
        for (int k4 = 0; k4 < 16; ++k4) {
            const int adv = (k4 < 15) ? 4 : 0;
            const float* Mn = Mp + adv * Nn;
            const int kn = kb0 + 4 * k4 + adv;
            vf4 p0 = *(const vf4*)(Mn);
            vf4 p1 = *(const vf4*)(Mn + Nn);
            vf4 p2 = *(const vf4*)(Mn + 2*Nn);
            vf4 p3 = *(const vf4*)(Mn + 3*Nn);
            vf4 nr0 = *(const vf4*)&rb1[kn], nr1 = *(const vf4*)&rb1[512 + kn];
            am0 += y0*r0.x; am0 += y1*r0.y; am0 += y2*r0.z; am0 += y3*r0.w;
            am1 += y0*r1.x; am1 += y1*r1.y; am1 += y2*r1.z; am1 += y3*r1.w;
            y0 = p0; y1 = p1; y2 = p2; y3 = p3;
            r0 = nr0; r1 = nr1;
            Mp = Mn;
        }
        *(vf4*)&PQ[kq * 1024 + 4*j]       = am0;
        *(vf4*)&PQ[kq * 1024 + 512 + 4*j] = am1;
        __syncthreads();
        {
            float s = qb1[t];
            #pragma unroll
            for (int pp = 0; pp < 8; ++pp) s += PQ[pp * 1024 + t];
            v0[t] = s;                                        // uS
            u_g[(row0 + (t >> 9)) * Nn + (t & 511)] = s;
        }
        __syncthreads();
    }

    // fused Schur assembly: this WG's two su columns
    {
        float* As = L + 1024;       // [64][33] = 2112 floats (qb1/qb2 dead)
        float* Ps = L + 3328;       // [16][64] (rb region dead)
        float accS = 0.f;
        const int e = t & 63;
        const int sub = t >> 6;                 // 0..15
        const int m_ = sub & 1, ch = sub >> 1;  // row, k-chunk 0..7
        for (int k0 = 0; k0 < Nn; k0 += 32) {
            __syncthreads();
            for (int i = t; i < 2048; i += 1024) {
                int ee = i >> 5, cc = i & 31;
                As[ee * 33 + cc] = A0[ee * Nn + k0 + cc];
            }
            __syncthreads();
            #pragma unroll
            for (int cc = 0; cc < 4; ++cc)
                accS += As[e * 33 + ch * 4 + cc] * v0[m_ * 512 + k0 + ch * 4 + cc];
        }
        Ps[sub * 64 + e] = accS;
        __syncthreads();
        if (t < 128) {
            int mm = t >> 6, ee = t & 63;
            float val = 0.f;
            #pragma unroll
            for (int c2 = 0; c2 < 8; ++c2) val += Ps[(mm + 2 * c2) * 64 + ee];
            int gr = row0 + mm;
            int jj = (gr < Bb) ? (64 + gr) : (gr - Bb);
            su[ee * NCr + jj] = val + ((jj >= 64) ? cvec[ee] : 0.f);
        }
    }
}

// ---------------------------------------------------------------------------
// k_lam_final: CG on S (64x64 SPD) for 128 columns, 1 wave/column, then
// out[b] = T_b - V * Lambda_b.  16 WGs x 512 thr.
// ---------------------------------------------------------------------------
__global__ __launch_bounds__(512) void k_lam_final(
    const float* __restrict__ u_g, const float* __restrict__ su,
    float* __restrict__ out)
{
    __shared__ float Sm[64][65];
    __shared__ float pb[8][64];
    const int t = threadIdx.x, w = t >> 6, lane = t & 63;

    for (int i = t; i < 64 * 64; i += 512)
        Sm[i >> 6][i & 63] = su[(i >> 6) * NCr + (i & 63)];
    __syncthreads();

    const int b = blockIdx.x * 8 + w;
    float srow[64];
    #pragma unroll
    for (int k = 0; k < 64; ++k) srow[k] = Sm[lane][k];

    float rhs = su[lane * NCr + 64 + b];
    float xv = 0.f, rv = rhs, pv = rv;
    float rr = wred(rv * rv);
    for (int itc = 0; itc < CGIT; ++itc) {
        pb[w][lane] = pv;
        float q = 0.f;
        #pragma unroll
        for (int k = 0; k < 64; ++k) q += srow[k] * pb[w][k];
        float pq = wred(pv * q);
        float alpha = rr / fmaxf(pq, 1e-30f);
        xv += alpha * pv;
        rv -= alpha * q;
        float rr2 = wred(rv * rv);
        float beta = rr2 / fmaxf(rr, 1e-30f);
        rr = rr2;
        pv = rv + beta * pv;
    }
    pb[w][lane] = xv;

    #pragma unroll
    for (int i = 0; i < 8; ++i) {
        int n = lane + 64 * i;
        float acc = u_g[b * Nn + n];
        #pragma unroll 4
        for (int e = 0; e < Ee; ++e)
            acc -= pb[w][e] * u_g[(Bb + e) * Nn + n];
        out[b * Nn + n] = acc;
    }
}

// ---------------------------------------------------------------------------
extern "C" void kernel_launch(void* const* d_in, const int* in_sizes, int n_in,
                              void* d_out, int out_size, void* d_ws, size_t ws_size,
                              hipStream_t stream)
{
    const float* x     = (const float*)d_in[0];
    const float* parms = (const float*)d_in[1];
    const float* Mm    = (const float*)d_in[2];
    const float* A0    = (const float*)d_in[3];
    // d_in[4] = B0 unused (F at zeros -> only c survives)
    const float* c     = (const float*)d_in[5];
    float* out = (float*)d_out;

    float* ws  = (float*)d_ws;
    float* Y   = ws;                         // 512*512
    float* u_g = ws + Nn * Nn;               // 192*512
    float* su  = ws + Nn * Nn + NCr * Nn;    // 64*192

    // ---- host: degree-9 Chebyshev poly for 1/h on [1, 3.12], even/odd split,
    // converted to Chebyshev basis on y = m^2 in [0, ymax] (all double).
    const double aa = 1.0, bbound = 3.12;
    const double th = 0.5 * (bbound + aa), de = 0.5 * (bbound - aa), sg = th / de;
    double rp[16] = {0}, dp[16] = {0}, xp[16] = {0}, hd[16];
    rp[0] = 1.0; dp[0] = 1.0 / th; xp[0] = 1.0 / th;
    double rho_prev = 1.0 / sg;
    for (int k = 1; k <= 9; ++k) {
        double rho = 1.0 / (2.0 * sg - rho_prev);
        double C1 = rho * rho_prev, C2 = 2.0 * rho / de;
        for (int i = 15; i >= 1; --i) hd[i] = dp[i - 1];
        hd[0] = 0.0;
        for (int i = 0; i < 16; ++i) {
            rp[i] -= hd[i];
            dp[i] = C1 * dp[i] + C2 * rp[i];
            xp[i] += dp[i];
        }
        rho_prev = rho;
    }
    // substitute h = 1 + m/2
    double pm[16] = {0};
    for (int k = 0; k <= 9; ++k) {
        double term[16] = {0}; term[0] = 1.0;
        for (int e = 0; e < k; ++e) {
            double nt[16] = {0};
            for (int i = 0; i <= e; ++i) { nt[i] += term[i]; nt[i + 1] += 0.5 * term[i]; }
            for (int i = 0; i <= e + 1; ++i) term[i] = nt[i];
        }
        for (int i = 0; i <= k; ++i) pm[i] += xp[k] * term[i];
    }
    double qm[8] = {0}, rm[8] = {0};
    for (int jj = 0; jj < 5; ++jj) { qm[jj] = pm[2 * jj]; rm[jj] = pm[2 * jj + 1]; }
    const double mmax = 2.0 * (bbound - 1.0);
    const double ymax = mmax * mmax;
    double cq[5] = {0}, cr[5] = {0};
    const int NP = 64;
    for (int i = 0; i < NP; ++i) {
        double thn = M_PI * (i + 0.5) / NP;
        double s = cos(thn);
        double y = 0.5 * ymax * (s + 1.0);
        double vq = 0, vr = 0;
        for (int d2 = 4; d2 >= 0; --d2) { vq = vq * y + qm[d2]; vr = vr * y + rm[d2]; }
        for (int jj = 0; jj < 5; ++jj) {
            cq[jj] += (2.0 / NP) * vq * cos(jj * thn);
            cr[jj] += (2.0 / NP) * vr * cos(jj * thn);
        }
    }
    cq[0] *= 0.5; cr[0] *= 0.5;
    CCoef cf;
    for (int jj = 0; jj < 5; ++jj) { cf.cq[jj] = (float)cq[jj]; cf.cr[jj] = (float)cr[jj]; }
    cf.f4 = (float)(4.0 / ymax);
    cf.f2 = (float)(2.0 / ymax);

    hipLaunchKernelGGL(k_prep,      dim3(64),  dim3(256),  0, stream, Mm, Y);
    hipLaunchKernelGGL(k_solve,     dim3(96),  dim3(1024), 0, stream,
                       x, parms, Mm, Y, A0, c, u_g, su, cf);
    hipLaunchKernelGGL(k_lam_final, dim3(16),  dim3(512),  0, stream, u_g, su, out);
}

// Round 8
// 190.616 us; speedup vs baseline: 1.1486x; 1.0942x over previous
//
#include <hip/hip_runtime.h>
#include <math.h>

// Problem constants: B=128, N=512, PD=512, E=64, gamma=1
#define Bb   128
#define Nn   512
#define Ee   64
#define NCr  192
#define CGIT 22

typedef float vf4 __attribute__((ext_vector_type(4)));

struct CCoef { float cq[5], cr[5], f4, f2; };

__device__ __forceinline__ float wred(float v)
{
    #pragma unroll
    for (int s = 32; s > 0; s >>= 1) v += __shfl_xor(v, s, 64);
    return v;
}

// ---------------------------------------------------------------------------
// k_prep2: partial Y = M @ M. Grid 512 = 64 output tiles (64x64) x split-K=8
// (K-slice of 64). 2 WGs/CU, 8 waves/CU -> latency actually hidden (the old
// 64-WG version ran 1 wave/SIMD and cost ~45 us). Deterministic partials.
// ---------------------------------------------------------------------------
__global__ __launch_bounds__(256) void k_prep2(const float* __restrict__ Mm,
                                               float* __restrict__ Ypart)
{
    __shared__ float As[16][68];   // [k][row]
    __shared__ float Bs[16][68];   // [k][col]
    const int t  = threadIdx.x;
    const int tx = t & 15, ty = t >> 4;
    const int tile = (int)(blockIdx.x >> 3);
    const int ks   = (int)(blockIdx.x & 7);
    const int r0 = (tile >> 3) * 64;
    const int c0 = (tile & 7) * 64;
    const int kbase = ks * 64;
    const int arow = t >> 2, ac4 = t & 3;   // A-load: 4 lanes x 16B contiguous

    vf4 acc0 = {0,0,0,0}, acc1 = {0,0,0,0}, acc2 = {0,0,0,0}, acc3 = {0,0,0,0};

    for (int k0 = kbase; k0 < kbase + 64; k0 += 16) {
        vf4 a = *(const vf4*)(Mm + (r0 + arow) * Nn + k0 + 4 * ac4);
        vf4 b = *(const vf4*)(Mm + (k0 + ty) * Nn + c0 + 4 * tx);
        __syncthreads();
        As[4*ac4+0][arow] = a.x; As[4*ac4+1][arow] = a.y;
        As[4*ac4+2][arow] = a.z; As[4*ac4+3][arow] = a.w;
        *(vf4*)&Bs[ty][4*tx] = b;
        __syncthreads();
        #pragma unroll
        for (int kk = 0; kk < 16; ++kk) {
            vf4 av = *(const vf4*)&As[kk][4*ty];
            vf4 bv = *(const vf4*)&Bs[kk][4*tx];
            acc0 += bv * av.x; acc1 += bv * av.y;
            acc2 += bv * av.z; acc3 += bv * av.w;
        }
    }
    float* yp = Ypart + ks * (Nn * Nn) + (r0 + 4*ty) * Nn + c0 + 4*tx;
    *(vf4*)(yp)        = acc0;
    *(vf4*)(yp + Nn)   = acc1;
    *(vf4*)(yp + 2*Nn) = acc2;
    *(vf4*)(yp + 3*Nn) = acc3;
}

// ---------------------------------------------------------------------------
// k_red: Y = sum of 8 split-K partials (fixed order -> deterministic).
// ---------------------------------------------------------------------------
__global__ __launch_bounds__(256) void k_red(const float* __restrict__ Ypart,
                                             float* __restrict__ Y)
{
    const int i4 = (int)blockIdx.x * 256 + threadIdx.x;   // vf4 index
    vf4 s = {0,0,0,0};
    #pragma unroll
    for (int ks = 0; ks < 8; ++ks)
        s += ((const vf4*)(Ypart + ks * (Nn * Nn)))[i4];
    ((vf4*)Y)[i4] = s;
}

// ---------------------------------------------------------------------------
// k_solve: 96 WGs x 1024 thr. WG owns rows {2wg,2wg+1} of [X-P | A0^T].
// p(M)v = q(Y)v + M r(Y)v via Clenshaw: 4 Y-passes + 1 M-pass, zero grid
// syncs. Split-K=8. Fused Schur assembly tail. (unchanged from round 7)
// ---------------------------------------------------------------------------
__global__ __launch_bounds__(1024) void k_solve(
    const float* __restrict__ x, const float* __restrict__ p,
    const float* __restrict__ Mm, const float* __restrict__ Y,
    const float* __restrict__ A0, const float* __restrict__ cvec,
    float* __restrict__ u_g, float* __restrict__ su, CCoef cf)
{
    __shared__ float L[21504];       // 84 KB
    float* v0  = L;                  // [2][512] input rows, later uS
    float* qb1 = L + 1024;
    float* qb2 = L + 2048;
    float* rb1 = L + 3072;
    float* rb2 = L + 4096;
    float* PQ  = L + 5120;           // [8][1024] split-K partials, q chain
    float* PR  = L + 13312;          // [8][1024] split-K partials, r chain

    const int t    = threadIdx.x;
    const int wg   = blockIdx.x;
    const int row0 = wg * 2;
    const int j    = t & 127;        // cols 4j..4j+3
    const int kq   = t >> 7;         // K-eighth 0..7
    const int kb0  = kq * 64;

    // build rows + Clenshaw init: b4 = c4*v0, b5 = 0 (one element per thread)
    {
        int m = t >> 9, n = t & 511, gr = row0 + m;
        float v = (gr < Bb) ? (x[gr * Nn + n] - p[gr * Nn + n])
                            : A0[(gr - Bb) * Nn + n];
        v0[t] = v;
        qb1[t] = cf.cq[4] * v; qb2[t] = 0.f;
        rb1[t] = cf.cr[4] * v; rb2[t] = 0.f;
    }
    __syncthreads();

    // 4 Y-passes (Clenshaw steps + final combine)
    for (int step = 0; step < 4; ++step) {
        vf4 aq0 = {0,0,0,0}, aq1 = {0,0,0,0}, ar0 = {0,0,0,0}, ar1 = {0,0,0,0};
        const float* Yp = Y + kb0 * Nn + 4 * j;
        vf4 y0 = *(const vf4*)(Yp);
        vf4 y1 = *(const vf4*)(Yp + Nn);
        vf4 y2 = *(const vf4*)(Yp + 2*Nn);
        vf4 y3 = *(const vf4*)(Yp + 3*Nn);
        vf4 q0 = *(const vf4*)&qb1[kb0],  q1 = *(const vf4*)&qb1[512 + kb0];
        vf4 r0 = *(const vf4*)&rb1[kb0],  r1 = *(const vf4*)&rb1[512 + kb0];
        #pragma unroll 4
        for (int k4 = 0; k4 < 16; ++k4) {
            const int adv = (k4 < 15) ? 4 : 0;
            const float* Yn = Yp + adv * Nn;
            const int kn = kb0 + 4 * k4 + adv;
            vf4 p0 = *(const vf4*)(Yn);
            vf4 p1 = *(const vf4*)(Yn + Nn);
            vf4 p2 = *(const vf4*)(Yn + 2*Nn);
            vf4 p3 = *(const vf4*)(Yn + 3*Nn);
            vf4 nq0 = *(const vf4*)&qb1[kn], nq1 = *(const vf4*)&qb1[512 + kn];
            vf4 nr0 = *(const vf4*)&rb1[kn], nr1 = *(const vf4*)&rb1[512 + kn];
            aq0 += y0*q0.x; aq0 += y1*q0.y; aq0 += y2*q0.z; aq0 += y3*q0.w;
            aq1 += y0*q1.x; aq1 += y1*q1.y; aq1 += y2*q1.z; aq1 += y3*q1.w;
            ar0 += y0*r0.x; ar0 += y1*r0.y; ar0 += y2*r0.z; ar0 += y3*r0.w;
            ar1 += y0*r1.x; ar1 += y1*r1.y; ar1 += y2*r1.z; ar1 += y3*r1.w;
            y0 = p0; y1 = p1; y2 = p2; y3 = p3;
            q0 = nq0; q1 = nq1; r0 = nr0; r1 = nr1;
            Yp = Yn;
        }
        *(vf4*)&PQ[kq * 1024 + 4*j]       = aq0;
        *(vf4*)&PQ[kq * 1024 + 512 + 4*j] = aq1;
        *(vf4*)&PR[kq * 1024 + 4*j]       = ar0;
        *(vf4*)&PR[kq * 1024 + 512 + 4*j] = ar1;
        __syncthreads();

        // combine 8 partials + Clenshaw update (one element per thread)
        {
            float yvq = 0.f, yvr = 0.f;
            #pragma unroll
            for (int pp = 0; pp < 8; ++pp) {
                yvq += PQ[pp * 1024 + t];
                yvr += PR[pp * 1024 + t];
            }
            if (step < 3) {
                float cqj = cf.cq[3 - step], crj = cf.cr[3 - step];
                float bnq = cqj * v0[t] + cf.f4 * yvq - 2.f * qb1[t] - qb2[t];
                float bnr = crj * v0[t] + cf.f4 * yvr - 2.f * rb1[t] - rb2[t];
                qb2[t] = qb1[t]; qb1[t] = bnq;
                rb2[t] = rb1[t]; rb1[t] = bnr;
            } else {   // final: F = c0 v0 + s b1 - b2,  s b1 = f2*Yb1 - b1
                float Fq = cf.cq[0] * v0[t] + cf.f2 * yvq - qb1[t] - qb2[t];
                float Fr = cf.cr[0] * v0[t] + cf.f2 * yvr - rb1[t] - rb2[t];
                qb1[t] = Fq; rb1[t] = Fr;
            }
        }
        __syncthreads();
    }

    // final M-pass: u = Fq + M*Fr
    {
        vf4 am0 = {0,0,0,0}, am1 = {0,0,0,0};
        const float* Mp = Mm + kb0 * Nn + 4 * j;
        vf4 y0 = *(const vf4*)(Mp);
        vf4 y1 = *(const vf4*)(Mp + Nn);
        vf4 y2 = *(const vf4*)(Mp + 2*Nn);
        vf4 y3 = *(const vf4*)(Mp + 3*Nn);
        vf4 r0 = *(const vf4*)&rb1[kb0], r1 = *(const vf4*)&rb1[512 + kb0];
        #pragma unroll 4
        for (int k4 = 0; k4 < 16; ++k4) {
            const int adv = (k4 < 15) ? 4 : 0;
            const float* Mn = Mp + adv * Nn;
            const int kn = kb0 + 4 * k4 + adv;
            vf4 p0 = *(const vf4*)(Mn);
            vf4 p1 = *(const vf4*)(Mn + Nn);
            vf4 p2 = *(const vf4*)(Mn + 2*Nn);
            vf4 p3 = *(const vf4*)(Mn + 3*Nn);
            vf4 nr0 = *(const vf4*)&rb1[kn], nr1 = *(const vf4*)&rb1[512 + kn];
            am0 += y0*r0.x; am0 += y1*r0.y; am0 += y2*r0.z; am0 += y3*r0.w;
            am1 += y0*r1.x; am1 += y1*r1.y; am1 += y2*r1.z; am1 += y3*r1.w;
            y0 = p0; y1 = p1; y2 = p2; y3 = p3;
            r0 = nr0; r1 = nr1;
            Mp = Mn;
        }
        *(vf4*)&PQ[kq * 1024 + 4*j]       = am0;
        *(vf4*)&PQ[kq * 1024 + 512 + 4*j] = am1;
        __syncthreads();
        {
            float s = qb1[t];
            #pragma unroll
            for (int pp = 0; pp < 8; ++pp) s += PQ[pp * 1024 + t];
            v0[t] = s;                                        // uS
            u_g[(row0 + (t >> 9)) * Nn + (t & 511)] = s;
        }
        __syncthreads();
    }

    // fused Schur assembly: this WG's two su columns
    {
        float* As = L + 1024;       // [64][33] = 2112 floats (qb1/qb2 dead)
        float* Ps = L + 3328;       // [16][64] (rb region dead)
        float accS = 0.f;
        const int e = t & 63;
        const int sub = t >> 6;                 // 0..15
        const int m_ = sub & 1, ch = sub >> 1;  // row, k-chunk 0..7
        for (int k0 = 0; k0 < Nn; k0 += 32) {
            __syncthreads();
            for (int i = t; i < 2048; i += 1024) {
                int ee = i >> 5, cc = i & 31;
                As[ee * 33 + cc] = A0[ee * Nn + k0 + cc];
            }
            __syncthreads();
            #pragma unroll
            for (int cc = 0; cc < 4; ++cc)
                accS += As[e * 33 + ch * 4 + cc] * v0[m_ * 512 + k0 + ch * 4 + cc];
        }
        Ps[sub * 64 + e] = accS;
        __syncthreads();
        if (t < 128) {
            int mm = t >> 6, ee = t & 63;
            float val = 0.f;
            #pragma unroll
            for (int c2 = 0; c2 < 8; ++c2) val += Ps[(mm + 2 * c2) * 64 + ee];
            int gr = row0 + mm;
            int jj = (gr < Bb) ? (64 + gr) : (gr - Bb);
            su[ee * NCr + jj] = val + ((jj >= 64) ? cvec[ee] : 0.f);
        }
    }
}

// ---------------------------------------------------------------------------
// k_lam_final: CG on S (64x64 SPD) for 128 columns, 1 wave/column, then
// out[b] = T_b - V * Lambda_b.  16 WGs x 512 thr. (unchanged)
// ---------------------------------------------------------------------------
__global__ __launch_bounds__(512) void k_lam_final(
    const float* __restrict__ u_g, const float* __restrict__ su,
    float* __restrict__ out)
{
    __shared__ float Sm[64][65];
    __shared__ float pb[8][64];
    const int t = threadIdx.x, w = t >> 6, lane = t & 63;

    for (int i = t; i < 64 * 64; i += 512)
        Sm[i >> 6][i & 63] = su[(i >> 6) * NCr + (i & 63)];
    __syncthreads();

    const int b = blockIdx.x * 8 + w;
    float srow[64];
    #pragma unroll
    for (int k = 0; k < 64; ++k) srow[k] = Sm[lane][k];

    float rhs = su[lane * NCr + 64 + b];
    float xv = 0.f, rv = rhs, pv = rv;
    float rr = wred(rv * rv);
    for (int itc = 0; itc < CGIT; ++itc) {
        pb[w][lane] = pv;
        float q = 0.f;
        #pragma unroll
        for (int k = 0; k < 64; ++k) q += srow[k] * pb[w][k];
        float pq = wred(pv * q);
        float alpha = rr / fmaxf(pq, 1e-30f);
        xv += alpha * pv;
        rv -= alpha * q;
        float rr2 = wred(rv * rv);
        float beta = rr2 / fmaxf(rr, 1e-30f);
        rr = rr2;
        pv = rv + beta * pv;
    }
    pb[w][lane] = xv;

    #pragma unroll
    for (int i = 0; i < 8; ++i) {
        int n = lane + 64 * i;
        float acc = u_g[b * Nn + n];
        #pragma unroll 4
        for (int e = 0; e < Ee; ++e)
            acc -= pb[w][e] * u_g[(Bb + e) * Nn + n];
        out[b * Nn + n] = acc;
    }
}

// ---------------------------------------------------------------------------
extern "C" void kernel_launch(void* const* d_in, const int* in_sizes, int n_in,
                              void* d_out, int out_size, void* d_ws, size_t ws_size,
                              hipStream_t stream)
{
    const float* x     = (const float*)d_in[0];
    const float* parms = (const float*)d_in[1];
    const float* Mm    = (const float*)d_in[2];
    const float* A0    = (const float*)d_in[3];
    // d_in[4] = B0 unused (F at zeros -> only c survives)
    const float* c     = (const float*)d_in[5];
    float* out = (float*)d_out;

    float* ws    = (float*)d_ws;
    float* Y     = ws;                               // 512*512
    float* Ypart = ws + Nn * Nn;                     // 8 * 512*512
    float* u_g   = ws + Nn * Nn + 8 * Nn * Nn;       // 192*512
    float* su    = u_g + NCr * Nn;                   // 64*192

    // ---- host: degree-9 Chebyshev poly for 1/h on [1, 3.12], even/odd split,
    // converted to Chebyshev basis on y = m^2 in [0, ymax] (all double).
    const double aa = 1.0, bbound = 3.12;
    const double th = 0.5 * (bbound + aa), de = 0.5 * (bbound - aa), sg = th / de;
    double rp[16] = {0}, dp[16] = {0}, xp[16] = {0}, hd[16];
    rp[0] = 1.0; dp[0] = 1.0 / th; xp[0] = 1.0 / th;
    double rho_prev = 1.0 / sg;
    for (int k = 1; k <= 9; ++k) {
        double rho = 1.0 / (2.0 * sg - rho_prev);
        double C1 = rho * rho_prev, C2 = 2.0 * rho / de;
        for (int i = 15; i >= 1; --i) hd[i] = dp[i - 1];
        hd[0] = 0.0;
        for (int i = 0; i < 16; ++i) {
            rp[i] -= hd[i];
            dp[i] = C1 * dp[i] + C2 * rp[i];
            xp[i] += dp[i];
        }
        rho_prev = rho;
    }
    // substitute h = 1 + m/2
    double pm[16] = {0};
    for (int k = 0; k <= 9; ++k) {
        double term[16] = {0}; term[0] = 1.0;
        for (int e = 0; e < k; ++e) {
            double nt[16] = {0};
            for (int i = 0; i <= e; ++i) { nt[i] += term[i]; nt[i + 1] += 0.5 * term[i]; }
            for (int i = 0; i <= e + 1; ++i) term[i] = nt[i];
        }
        for (int i = 0; i <= k; ++i) pm[i] += xp[k] * term[i];
    }
    double qm[8] = {0}, rm[8] = {0};
    for (int jj = 0; jj < 5; ++jj) { qm[jj] = pm[2 * jj]; rm[jj] = pm[2 * jj + 1]; }
    const double mmax = 2.0 * (bbound - 1.0);
    const double ymax = mmax * mmax;
    double cq[5] = {0}, cr[5] = {0};
    const int NP = 64;
    for (int i = 0; i < NP; ++i) {
        double thn = M_PI * (i + 0.5) / NP;
        double s = cos(thn);
        double y = 0.5 * ymax * (s + 1.0);
        double vq = 0, vr = 0;
        for (int d2 = 4; d2 >= 0; --d2) { vq = vq * y + qm[d2]; vr = vr * y + rm[d2]; }
        for (int jj = 0; jj < 5; ++jj) {
            cq[jj] += (2.0 / NP) * vq * cos(jj * thn);
            cr[jj] += (2.0 / NP) * vr * cos(jj * thn);
        }
    }
    cq[0] *= 0.5; cr[0] *= 0.5;
    CCoef cf;
    for (int jj = 0; jj < 5; ++jj) { cf.cq[jj] = (float)cq[jj]; cf.cr[jj] = (float)cr[jj]; }
    cf.f4 = (float)(4.0 / ymax);
    cf.f2 = (float)(2.0 / ymax);

    hipLaunchKernelGGL(k_prep2,     dim3(512), dim3(256),  0, stream, Mm, Ypart);
    hipLaunchKernelGGL(k_red,       dim3(256), dim3(256),  0, stream, Ypart, Y);
    hipLaunchKernelGGL(k_solve,     dim3(96),  dim3(1024), 0, stream,
                       x, parms, Mm, Y, A0, c, u_g, su, cf);
    hipLaunchKernelGGL(k_lam_final, dim3(16),  dim3(512),  0, stream, u_g, su, out);
}